// Round 13
// baseline (299.991 us; speedup 1.0000x reference)
//
#include <hip/hip_runtime.h>
#include <hip/hip_bf16.h>

#define DEV static __device__ __forceinline__

typedef unsigned short ushort;
typedef __attribute__((ext_vector_type(8))) short short8;
typedef __attribute__((ext_vector_type(8))) ushort ushort8;
typedef __attribute__((ext_vector_type(4))) ushort ushortx4;
typedef __attribute__((ext_vector_type(4))) float accv;

DEV ushort f2bf(float f) {
    __hip_bfloat16 h = __float2bfloat16(f);   // RNE
    return reinterpret_cast<ushort&>(h);
}

// ---------------------------------------------------------------------------
// Static device workspace
// sred: [layer][co][32]; slots sub*3+{0,1} for sub=0..7 (sum, sumsq)
// mcnt: [layer][32]; slots sub*4 (mask count, co-independent)
// ---------------------------------------------------------------------------
__device__ float    g_sred[5 * 128 * 32];
__device__ float    g_mcnt[160];
__device__ float    g_y1[2097152];                    // (2,32,32^3) fp32 NCV
__device__ __align__(16) ushort g_y1b[2097152];       // (2,32^3,32) bf16 VC
__device__ float    g_m1[65536];
__device__ float    g_y2[524288];
__device__ __align__(16) ushort g_y2b[524288];
__device__ float    g_m2[8192];
__device__ float    g_y3[131072];
__device__ __align__(16) ushort g_y3b[131072];
__device__ float    g_m3[1024];
__device__ float    g_t1[1048576];
__device__ __align__(16) ushort g_t1b[1048576];
__device__ float    g_mt1[8192];
__device__ float    g_mt2[65536];
__device__ float    g_t2[4194304];                    // conv5 post-act out (fp32 NCV)
__device__ __align__(16) ushort g_x0b[2097152];       // (2,64^3,4) bf16 VC masked feat
// split-K partial buffers
__device__ float    g_p2[4194304];                    // 8  x 524288
__device__ float    g_p3[4194304];                    // 32 x 131072
__device__ float    g_p4[8388608];                    // 8  x 1048576
// K-major weights
__device__ __align__(16) ushort g_wb1[8192];          // [32co][256k], k=tap*4+ci
__device__ __align__(16) ushort g_wb2[131072];
__device__ __align__(16) ushort g_wb3[524288];
__device__ __align__(16) ushort g_wb4[1048576];
__device__ __align__(16) ushort g_wb5[524288];
__device__ float    g_fwt[2048];                      // [k=64][co=32] fp32

// ---------------------------------------------------------------------------
// prep_all: zero + write-coalesced (output-major) weight transposes + x0b + mask1
// ranges: [0,96) setup | [96,608) wb2 | [608,2656) wb3 | [2656,6752) wb4
//         [6752,8800) wb5 | [8800,10848) x0b | [10848,11104) mask1
// ---------------------------------------------------------------------------
__global__ __launch_bounds__(256)
void prep_all_kernel(const float* __restrict__ w1, const float* __restrict__ fw,
                     const float* __restrict__ w2, const float* __restrict__ w3,
                     const float* __restrict__ tw1, const float* __restrict__ tw2,
                     const float* __restrict__ feat, const float* __restrict__ mask) {
    int blk = blockIdx.x, tid = threadIdx.x;
    if (blk < 96) {
        int idx = blk * 256 + tid;
        if (idx < 20480) g_sred[idx] = 0.f;
        if (idx < 160)   g_mcnt[idx] = 0.f;
        if (idx < 8192) {
            int co = idx >> 8, r = idx & 255;
            int tap = r >> 2, ci = r & 3;
            g_wb1[idx] = f2bf(w1[co * 256 + ci * 64 + tap]);
        }
        if (idx < 2048) { int co = idx >> 6, kg = idx & 63; g_fwt[kg * 32 + co] = fw[idx]; }
    } else if (blk < 608) {
        int idx = (blk - 96) * 256 + tid;               // out-major: co,tap,ci
        int co = idx >> 11, rem = idx & 2047;
        int tap = rem >> 5, ci = rem & 31;
        g_wb2[idx] = f2bf(w2[co * 2048 + ci * 64 + tap]);
    } else if (blk < 2656) {
        int idx = (blk - 608) * 256 + tid;
        int co = idx >> 12, rem = idx & 4095;
        int tap = rem >> 6, ci = rem & 63;
        g_wb3[idx] = f2bf(w3[co * 4096 + ci * 64 + tap]);
    } else if (blk < 6752) {
        int idx = (blk - 2656) * 256 + tid;             // [8p][128co][8t][128ci]
        int parity = idx >> 17, rem = idx & 0x1FFFF;
        int co = rem >> 10, rem2 = rem & 1023;
        int t = rem2 >> 7, ci = rem2 & 127;
        int td = (t >> 2) & 1, th = (t >> 1) & 1, tw = t & 1;
        int pd = (parity >> 2) & 1, ph = (parity >> 1) & 1, pw = parity & 1;
        int kd = 3 - 2 * td - pd, kh = 3 - 2 * th - ph, kw = 3 - 2 * tw - pw;
        g_wb4[idx] = f2bf(tw1[co * 8192 + ci * 64 + kd * 16 + kh * 4 + kw]);
    } else if (blk < 8800) {
        int idx = (blk - 6752) * 256 + tid;             // [8p][64co][8t][128ci]
        int parity = idx >> 16, rem = idx & 0xFFFF;
        int co = rem >> 10, rem2 = rem & 1023;
        int t = rem2 >> 7, ci = rem2 & 127;
        int td = (t >> 2) & 1, th = (t >> 1) & 1, tw = t & 1;
        int pd = (parity >> 2) & 1, ph = (parity >> 1) & 1, pw = parity & 1;
        int kd = 3 - 2 * td - pd, kh = 3 - 2 * th - ph, kw = 3 - 2 * tw - pw;
        g_wb5[idx] = f2bf(tw2[co * 8192 + ci * 64 + kd * 16 + kh * 4 + kw]);
    } else if (blk < 10848) {
        int idx = (blk - 8800) * 256 + tid;
        int b = idx >> 18, v = idx & 0x3FFFF;
        float mv = mask[idx] > 0.5f ? 1.f : 0.f;
        ushort pk[4];
#pragma unroll
        for (int c = 0; c < 4; c++) pk[c] = f2bf(feat[((b * 4 + c) << 18) + v] * mv);
        *(ushortx4*)&g_x0b[(size_t)idx * 4] = (ushortx4){pk[0], pk[1], pk[2], pk[3]};
    } else {
        int idx = (blk - 10848) * 256 + tid;            // mask1
        int b = idx >> 15, v = idx & 0x7FFF;
        int od = v >> 10, rem = v & 1023;
        int oh = rem >> 5, ow = rem & 31;
        const float* mp = mask + ((size_t)b << 18);
        float acc = 0.f;
        for (int kd = 0; kd < 4; kd++) {
            int id = 2 * od - 1 + kd;
            if ((unsigned)id >= 64u) continue;
            for (int kh = 0; kh < 4; kh++) {
                int ih = 2 * oh - 1 + kh;
                if ((unsigned)ih >= 64u) continue;
                const float* row = mp + ((size_t)id * 64 + ih) * 64;
                for (int kw = 0; kw < 4; kw++) {
                    int iw = 2 * ow - 1 + kw;
                    if ((unsigned)iw < 64u && row[iw] > 0.5f) acc += 1.f;
                }
            }
        }
        g_m1[idx] = acc > 0.f ? 1.f : 0.f;
    }
}

// ---------------------------------------------------------------------------
// mask dilation bodies with explicit block index (fused into bn kernels)
// ---------------------------------------------------------------------------
DEV void mask_down_blk(const float* mprev, float* mout, int logDin, int logDo, int blk) {
    int Din = 1 << logDin, Do = 1 << logDo;
    int idx = blk * 256 + threadIdx.x;
    int b = idx >> (3 * logDo), v = idx & ((1 << (3 * logDo)) - 1);
    int od = v >> (2 * logDo), rem = v & ((1 << (2 * logDo)) - 1);
    int oh = rem >> logDo, ow = rem & (Do - 1);
    const float* mp = mprev + ((size_t)b << (3 * logDin));
    float acc = 0.f;
    for (int kd = 0; kd < 4; kd++) {
        int id = 2 * od - 1 + kd;
        if ((unsigned)id >= (unsigned)Din) continue;
        for (int kh = 0; kh < 4; kh++) {
            int ih = 2 * oh - 1 + kh;
            if ((unsigned)ih >= (unsigned)Din) continue;
            const float* row = mp + ((size_t)id * Din + ih) * Din;
            for (int kw = 0; kw < 4; kw++) {
                int iw = 2 * ow - 1 + kw;
                if ((unsigned)iw < (unsigned)Din) acc += row[iw];
            }
        }
    }
    mout[idx] = acc > 0.f ? 1.f : 0.f;
}

DEV void mask_up_blk(const float* mprev, float* mout, int logDin, int logDo, int blk) {
    int Din = 1 << logDin, Do = 1 << logDo;
    int idx = blk * 256 + threadIdx.x;
    int b = idx >> (3 * logDo), v = idx & ((1 << (3 * logDo)) - 1);
    int od = v >> (2 * logDo), rem = v & ((1 << (2 * logDo)) - 1);
    int oh = rem >> logDo, ow = rem & (Do - 1);
    const float* mp = mprev + ((size_t)b << (3 * logDin));
    float acc = 0.f;
    for (int kd = 0; kd < 4; kd++) {
        int u = od + kd - 2; if (u < 0 || (u & 1)) continue;
        int id = u >> 1; if (id >= Din) continue;
        for (int kh = 0; kh < 4; kh++) {
            int uh = oh + kh - 2; if (uh < 0 || (uh & 1)) continue;
            int ih = uh >> 1; if (ih >= Din) continue;
            const float* row = mp + ((size_t)id * Din + ih) * Din;
            for (int kw = 0; kw < 4; kw++) {
                int uw = ow + kw - 2; if (uw < 0 || (uw & 1)) continue;
                int iw = uw >> 1; if (iw >= Din) continue;
                acc += row[iw];
            }
        }
    }
    mout[idx] = acc > 0.f ? 1.f : 0.f;
}

// ---------------------------------------------------------------------------
// bf16 MFMA implicit-GEMM, register-prefetch pipelined, hoisted B-decode.
// EPI=0: raw store (split-K partials). EPI=1 (MODE1,SPLITK=1): fused
// bias+mask+leaky store + per-co stats (sub-slotted atomics).
// ---------------------------------------------------------------------------
template<int MODE, int MT, int NT, int CIN, int COUT, int LOGDI, int LOGDO, int SPLITK, int EPI>
DEV void mfma_gemm_body(const ushort* __restrict__ xb, const ushort* __restrict__ wb,
                        float* __restrict__ y, const float* __restrict__ bias,
                        const float* __restrict__ m2s, float* __restrict__ sredL,
                        float* __restrict__ mcntL) {
    constexpr int KT = 32;
    constexpr int K  = (MODE == 1) ? CIN * 8 : CIN * 64;
    constexpr int KSEG = K / SPLITK;
    constexpr int LDA = 40;
    constexpr int MTW = MT / 32, NTW = NT / 32;
    constexpr int AR = MT * 4 / 256, BR = NT * 4 / 256;
    constexpr int LCIN = (CIN == 32) ? 5 : ((CIN == 64) ? 6 : 7);
    constexpr int Din = 1 << LOGDI, Do = 1 << LOGDO;
    constexpr int DvoxI = 1 << (3 * LOGDI), DvoxO = 1 << (3 * LOGDO);

    __shared__ __align__(16) ushort As[MT * LDA];
    __shared__ __align__(16) ushort Bs[NT * LDA];
    __shared__ float sb[(EPI == 1) ? COUT : 1];

    const int tid = threadIdx.x;
    const int bx = blockIdx.x;
    int pd = 0, ph = 0, pw = 0, ks = 0;
    const ushort* wp = wb;
    if constexpr (MODE == 1) {
        int z = blockIdx.z;
        pd = (z >> 2) & 1; ph = (z >> 1) & 1; pw = z & 1; ks = z >> 3;
        wp = wb + (size_t)(z & 7) * COUT * CIN * 8;
    } else {
        ks = blockIdx.z;
    }

    if constexpr (EPI == 1) { if (tid < COUT) sb[tid] = bias[tid]; }

    const int wv = tid >> 6, lane = tid & 63;
    const int mw = wv & 1, nw = wv >> 1;
    const int lr = lane & 15, quad = lane >> 4;

    // hoisted per-slot B voxel decode
    int rB[BR], dB[BR], hB[BR], wBv[BR];
#pragma unroll
    for (int r = 0; r < BR; r++) {
        int slot = r * 256 + tid;
        int n = slot >> 2;
        int vg = bx * NT + n;
        if constexpr (MODE == 0) {
            rB[r] = vg >> (3 * LOGDO);
            int vv = vg & (DvoxO - 1);
            dB[r] = 2 * (vv >> (2 * LOGDO)) - 1;
            hB[r] = 2 * ((vv >> LOGDO) & (Do - 1)) - 1;
            wBv[r] = 2 * (vv & (Do - 1)) - 1;
        } else {
            rB[r] = vg >> (3 * LOGDI);
            int vv = vg & (DvoxI - 1);
            dB[r] = (vv >> (2 * LOGDI)) + pd - 1;
            hB[r] = ((vv >> LOGDI) & (Din - 1)) + ph - 1;
            wBv[r] = (vv & (Din - 1)) + pw - 1;
        }
    }

    auto gatherA = [&](int kt, ushort8* pa) {
#pragma unroll
        for (int r = 0; r < AR; r++) {
            int slot = r * 256 + tid;
            int m = slot >> 2, oct = slot & 3;
            pa[r] = *(const ushort8*)&wp[(size_t)m * K + kt + oct * 8];
        }
    };
    auto gatherB = [&](int kt, ushort8* pb) {
        int tap = kt >> LCIN;
        int cib = kt & (CIN - 1);
        int id_d, ih_d, iw_d;
        if constexpr (MODE == 0) { id_d = tap >> 4; ih_d = (tap >> 2) & 3; iw_d = tap & 3; }
        else                     { id_d = (tap >> 2) & 1; ih_d = (tap >> 1) & 1; iw_d = tap & 1; }
#pragma unroll
        for (int r = 0; r < BR; r++) {
            int oct = (r * 256 + tid) & 3;
            int ci0 = cib + oct * 8;
            int id = dB[r] + id_d, ih = hB[r] + ih_d, iw = wBv[r] + iw_d;
            ushort8 v = (ushort8){0, 0, 0, 0, 0, 0, 0, 0};
            if ((unsigned)id < (unsigned)Din && (unsigned)ih < (unsigned)Din &&
                (unsigned)iw < (unsigned)Din)
                v = *(const ushort8*)&xb[((size_t)rB[r] * DvoxI +
                                          (id << (2 * LOGDI)) + (ih << LOGDI) + iw) * CIN + ci0];
            pb[r] = v;
        }
    };

    accv acc[MTW][NTW];
#pragma unroll
    for (int mt = 0; mt < MTW; mt++)
#pragma unroll
        for (int nt = 0; nt < NTW; nt++) acc[mt][nt] = (accv){0.f, 0.f, 0.f, 0.f};

    const int kbeg = ks * KSEG, kend = kbeg + KSEG;
    ushort8 pa[AR], pb[BR], qa[AR], qb[BR];
    gatherA(kbeg, pa);
    gatherB(kbeg, pb);

    for (int kt = kbeg; kt < kend; kt += KT) {
        __syncthreads();
#pragma unroll
        for (int r = 0; r < AR; r++) {
            int slot = r * 256 + tid;
            int m = slot >> 2, oct = slot & 3;
            *(ushort8*)&As[m * LDA + oct * 8] = pa[r];
        }
#pragma unroll
        for (int r = 0; r < BR; r++) {
            int slot = r * 256 + tid;
            int n = slot >> 2, oct = slot & 3;
            *(ushort8*)&Bs[n * LDA + oct * 8] = pb[r];
        }
        __syncthreads();
        bool more = (kt + KT) < kend;
        if (more) { gatherA(kt + KT, qa); gatherB(kt + KT, qb); }

        short8 af[MTW], bfr[NTW];
#pragma unroll
        for (int mt = 0; mt < MTW; mt++)
            af[mt] = *(const short8*)&As[((mw * MTW + mt) * 16 + lr) * LDA + quad * 8];
#pragma unroll
        for (int nt = 0; nt < NTW; nt++)
            bfr[nt] = *(const short8*)&Bs[((nw * NTW + nt) * 16 + lr) * LDA + quad * 8];
#pragma unroll
        for (int mt = 0; mt < MTW; mt++)
#pragma unroll
            for (int nt = 0; nt < NTW; nt++)
                acc[mt][nt] = __builtin_amdgcn_mfma_f32_16x16x32_bf16(
                    af[mt], bfr[nt], acc[mt][nt], 0, 0, 0);
        if (more) {
#pragma unroll
            for (int r = 0; r < AR; r++) pa[r] = qa[r];
#pragma unroll
            for (int r = 0; r < BR; r++) pb[r] = qb[r];
        }
    }

    if constexpr (EPI == 0) {
        float* yp = y + (size_t)ks * (2 * COUT * DvoxO);
#pragma unroll
        for (int mt = 0; mt < MTW; mt++) {
#pragma unroll
            for (int nt = 0; nt < NTW; nt++) {
#pragma unroll
                for (int r = 0; r < 4; r++) {
                    int co = (mw * MTW + mt) * 16 + quad * 4 + r;
                    int vg = bx * NT + (nw * NTW + nt) * 16 + lr;
                    size_t idx;
                    if constexpr (MODE == 1) {
                        int b = vg >> (3 * LOGDI);
                        int vv = vg & (DvoxI - 1);
                        int odp = vv >> (2 * LOGDI), ohp = (vv >> LOGDI) & (Din - 1), owp = vv & (Din - 1);
                        int od = 2 * odp + pd, oh = 2 * ohp + ph, ow = 2 * owp + pw;
                        idx = (((size_t)(b * COUT + co)) << (3 * LOGDO)) +
                              (od << (2 * LOGDO)) + (oh << LOGDO) + ow;
                    } else {
                        int b = vg >> (3 * LOGDO);
                        int off = vg & (DvoxO - 1);
                        idx = (((size_t)(b * COUT + co)) << (3 * LOGDO)) + off;
                    }
                    yp[idx] = acc[mt][nt][r];
                }
            }
        }
    } else {
        // fused bias+mask+leaky store + stats (MODE 1, SPLITK 1)
        __shared__ float sS[COUT][2], sQ[COUT][2], sM[2];
        float sum_[MTW][4], ssq_[MTW][4];
#pragma unroll
        for (int mt = 0; mt < MTW; mt++)
#pragma unroll
            for (int r = 0; r < 4; r++) { sum_[mt][r] = 0.f; ssq_[mt][r] = 0.f; }
        float smv = 0.f;
#pragma unroll
        for (int nt = 0; nt < NTW; nt++) {
            int vg = bx * NT + (nw * NTW + nt) * 16 + lr;
            int b = vg >> (3 * LOGDI);
            int vv = vg & (DvoxI - 1);
            int odp = vv >> (2 * LOGDI), ohp = (vv >> LOGDI) & (Din - 1), owp = vv & (Din - 1);
            int od = 2 * odp + pd, oh = 2 * ohp + ph, ow = 2 * owp + pw;
            size_t off = (od << (2 * LOGDO)) + (oh << LOGDO) + ow;
            float mv = m2s[((size_t)b << (3 * LOGDO)) + off];
            if (quad == 0) smv += mv;
#pragma unroll
            for (int mt = 0; mt < MTW; mt++) {
#pragma unroll
                for (int r = 0; r < 4; r++) {
                    int co = (mw * MTW + mt) * 16 + quad * 4 + r;
                    float yv = (acc[mt][nt][r] + sb[co]) * mv;
                    yv = yv >= 0.f ? yv : 0.01f * yv;
                    y[(((size_t)(b * COUT + co)) << (3 * LOGDO)) + off] = yv;
                    sum_[mt][r] += yv; ssq_[mt][r] += yv * yv;
                }
            }
        }
#pragma unroll
        for (int mt = 0; mt < MTW; mt++)
#pragma unroll
            for (int r = 0; r < 4; r++)
#pragma unroll
                for (int o = 8; o; o >>= 1) {
                    sum_[mt][r] += __shfl_down(sum_[mt][r], o, 16);
                    ssq_[mt][r] += __shfl_down(ssq_[mt][r], o, 16);
                }
#pragma unroll
        for (int o = 8; o; o >>= 1) smv += __shfl_down(smv, o, 16);
        if (lr == 0) {
#pragma unroll
            for (int mt = 0; mt < MTW; mt++)
#pragma unroll
                for (int r = 0; r < 4; r++) {
                    int co = (mw * MTW + mt) * 16 + quad * 4 + r;
                    sS[co][nw] = sum_[mt][r]; sQ[co][nw] = ssq_[mt][r];
                }
            if (quad == 0 && mw == 0) sM[nw] = smv;
        }
        __syncthreads();
        int sub = (bx + blockIdx.z) & 7;
        if (tid < COUT) {
            atomicAdd(&sredL[tid * 32 + sub * 3],     sS[tid][0] + sS[tid][1]);
            atomicAdd(&sredL[tid * 32 + sub * 3 + 1], sQ[tid][0] + sQ[tid][1]);
        }
        if (tid == COUT) atomicAdd(&mcntL[sub * 4], sM[0] + sM[1]);
    }
}

__global__ __launch_bounds__(256)
void conv2_kernel() { mfma_gemm_body<0, 64, 128, 32, 64, 5, 4, 8, 0>(g_y1b, g_wb2, g_p2, nullptr, nullptr, nullptr, nullptr); }
__global__ __launch_bounds__(256)
void conv3_kernel() { mfma_gemm_body<0, 128, 64, 64, 128, 4, 3, 32, 0>(g_y2b, g_wb3, g_p3, nullptr, nullptr, nullptr, nullptr); }
__global__ __launch_bounds__(256)
void conv4_kernel() { mfma_gemm_body<1, 128, 128, 128, 128, 3, 4, 8, 0>(g_y3b, g_wb4, g_p4, nullptr, nullptr, nullptr, nullptr); }
__global__ __launch_bounds__(256)
void conv5_kernel(const float* b5) { mfma_gemm_body<1, 64, 128, 128, 64, 4, 5, 1, 1>(g_t1b, g_wb5, g_t2, b5, g_mt2, g_sred + 16384, g_mcnt + 128); }

// ---------------------------------------------------------------------------
// conv1: bf16 MFMA + fused stats (stats1 eliminated). grid 1024.
// ---------------------------------------------------------------------------
__global__ __launch_bounds__(256)
void conv1_kernel(const float* __restrict__ bias) {
    constexpr int LDA = 40;
    __shared__ __align__(16) ushort As[32 * LDA];
    __shared__ __align__(16) ushort Bs[64 * LDA];
    __shared__ float sS[32][4], sQ[32][4], sM[4];
    const int tid = threadIdx.x, bx = blockIdx.x;
    const int wv = tid >> 6, lane = tid & 63;
    const int lr = lane & 15, quad = lane >> 4;

    const int nB = tid >> 2, octB = tid & 3;
    const int vgB = bx * 64 + nB;
    const int bB = vgB >> 15, vB = vgB & 32767;
    const int odB = vB >> 10, ohB = (vB >> 5) & 31, owB = vB & 31;

    auto gatherA = [&](int kt, ushort8& pa) {
        if (tid < 128) {
            int m = tid >> 2, oct = tid & 3;
            pa = *(const ushort8*)&g_wb1[m * 256 + kt + oct * 8];
        }
    };
    auto gatherB = [&](int kt, ushort8& pb) {
        int kg0 = kt + octB * 8;
        int t0 = kg0 >> 2;
        int kd = t0 >> 4, kh = (t0 >> 2) & 3, kw0 = t0 & 3;
        int id = 2 * odB - 1 + kd;
        int ih = 2 * ohB - 1 + kh;
        int iw0 = 2 * owB - 1 + kw0;
        ushort8 v = (ushort8){0, 0, 0, 0, 0, 0, 0, 0};
        if ((unsigned)id < 64u && (unsigned)ih < 64u) {
            const ushort* base = g_x0b + ((((size_t)bB << 18) + (id << 12) + (ih << 6)) << 2);
            if (iw0 >= 0 && iw0 + 1 < 64) {
                v = *(const ushort8*)&base[iw0 << 2];
            } else {
                if ((unsigned)iw0 < 64u) {
                    ushortx4 h = *(const ushortx4*)&base[iw0 << 2];
                    v[0] = h[0]; v[1] = h[1]; v[2] = h[2]; v[3] = h[3];
                }
                if ((unsigned)(iw0 + 1) < 64u) {
                    ushortx4 h = *(const ushortx4*)&base[(iw0 + 1) << 2];
                    v[4] = h[0]; v[5] = h[1]; v[6] = h[2]; v[7] = h[3];
                }
            }
        }
        pb = v;
    };

    accv acc[2];
    acc[0] = (accv){0.f, 0.f, 0.f, 0.f};
    acc[1] = (accv){0.f, 0.f, 0.f, 0.f};
    ushort8 pa, pb, qa, qb;
    gatherA(0, pa); gatherB(0, pb);

    for (int kt = 0; kt < 256; kt += 32) {
        __syncthreads();
        if (tid < 128) { int m = tid >> 2, oct = tid & 3; *(ushort8*)&As[m * LDA + oct * 8] = pa; }
        *(ushort8*)&Bs[nB * LDA + octB * 8] = pb;
        __syncthreads();
        bool more = kt < 224;
        if (more) { gatherA(kt + 32, qa); gatherB(kt + 32, qb); }

        short8 b8 = *(const short8*)&Bs[(wv * 16 + lr) * LDA + quad * 8];
#pragma unroll
        for (int mt = 0; mt < 2; mt++) {
            short8 a8 = *(const short8*)&As[(mt * 16 + lr) * LDA + quad * 8];
            acc[mt] = __builtin_amdgcn_mfma_f32_16x16x32_bf16(a8, b8, acc[mt], 0, 0, 0);
        }
        if (more) { pa = qa; pb = qb; }
    }

    // epilogue: bias+mask+leaky + fused stats
    int vg = bx * 64 + wv * 16 + lr;
    int b = vg >> 15, off = vg & 32767;
    float mv = g_m1[((size_t)b << 15) + off];
    float sum_[2][4], ssq_[2][4];
#pragma unroll
    for (int mt = 0; mt < 2; mt++) {
#pragma unroll
        for (int r = 0; r < 4; r++) {
            int co = mt * 16 + quad * 4 + r;
            float yv = (acc[mt][r] + bias[co]) * mv;
            yv = yv >= 0.f ? yv : 0.01f * yv;
            g_y1[(((size_t)(b * 32 + co)) << 15) + off] = yv;
            sum_[mt][r] = yv; ssq_[mt][r] = yv * yv;
        }
    }
    float smv = (quad == 0) ? mv : 0.f;
#pragma unroll
    for (int mt = 0; mt < 2; mt++)
#pragma unroll
        for (int r = 0; r < 4; r++)
#pragma unroll
            for (int o = 8; o; o >>= 1) {
                sum_[mt][r] += __shfl_down(sum_[mt][r], o, 16);
                ssq_[mt][r] += __shfl_down(ssq_[mt][r], o, 16);
            }
#pragma unroll
    for (int o = 8; o; o >>= 1) smv += __shfl_down(smv, o, 16);
    if (lr == 0) {
#pragma unroll
        for (int mt = 0; mt < 2; mt++)
#pragma unroll
            for (int r = 0; r < 4; r++) {
                int co = mt * 16 + quad * 4 + r;
                sS[co][wv] = sum_[mt][r]; sQ[co][wv] = ssq_[mt][r];
            }
        if (quad == 0) sM[wv] = smv;
    }
    __syncthreads();
    int sub = bx & 7;
    if (tid < 32) {
        atomicAdd(&g_sred[tid * 32 + sub * 3],     sS[tid][0] + sS[tid][1] + sS[tid][2] + sS[tid][3]);
        atomicAdd(&g_sred[tid * 32 + sub * 3 + 1], sQ[tid][0] + sQ[tid][1] + sQ[tid][2] + sQ[tid][3]);
    }
    if (tid == 32) atomicAdd(&g_mcnt[sub * 4], sM[0] + sM[1] + sM[2] + sM[3]);
}

// ---------------------------------------------------------------------------
// final: fp32 1x1x1; t2 is post-activation, apply BN*mask on load. grid 1024.
// ---------------------------------------------------------------------------
__global__ __launch_bounds__(256)
void final_kernel(const float* __restrict__ fb, const float* __restrict__ tg2,
                  const float* __restrict__ tbe2, float* __restrict__ out) {
    __shared__ float As[1024];
    __shared__ float Bs[2048];
    __shared__ float sc5[64], sh5[64];
    const int tid = threadIdx.x, tc = tid & 15, tv = tid >> 4;
    const int bx = blockIdx.x;

    if (tid < 64) {
        const float* sred = g_sred + 16384;
        const float* mc = g_mcnt + 128;
        float n = 0.f, su = 0.f, sq = 0.f;
#pragma unroll
        for (int s = 0; s < 8; s++) {
            n += mc[s * 4];
            su += sred[tid * 32 + s * 3];
            sq += sred[tid * 32 + s * 3 + 1];
        }
        n = fmaxf(n, 1.f);
        float mean = su / n;
        float var = fmaxf(sq / n - mean * mean, 0.f);
        float rstd = rsqrtf(var + 1e-5f);
        float s = tg2[tid] * rstd;
        sc5[tid] = s; sh5[tid] = tbe2[tid] - mean * s;
    }

    float acc[2][4] = {{0.f}};
    for (int kt = 0; kt < 64; kt += 32) {
        __syncthreads();
#pragma unroll
        for (int e = 0; e < 4; e++) As[e * 256 + tid] = g_fwt[kt * 32 + e * 256 + tid];
#pragma unroll
        for (int e = 0; e < 8; e++) {
            int j = e * 256 + tid;
            int kk = j >> 6, n = j & 63;
            int kg = kt + kk;
            int vg = bx * 64 + n;
            int b = vg >> 15, v = vg & 32767;
            float raw = g_t2[(((size_t)(b * 64 + kg)) << 15) + v];
            float mv = g_mt2[((size_t)b << 15) + v];
            Bs[kk * 64 + n] = (raw * sc5[kg] + sh5[kg]) * mv;
        }
        __syncthreads();
#pragma unroll
        for (int kk = 0; kk < 32; kk++) {
            float2 a2 = *(const float2*)&As[kk * 32 + tc * 2];
            float4 b4 = *(const float4*)&Bs[kk * 64 + tv * 4];
            float a[2] = {a2.x, a2.y};
            float bb[4] = {b4.x, b4.y, b4.z, b4.w};
#pragma unroll
            for (int r = 0; r < 2; r++)
#pragma unroll
                for (int c = 0; c < 4; c++) acc[r][c] = fmaf(a[r], bb[c], acc[r][c]);
        }
    }
#pragma unroll
    for (int r = 0; r < 2; r++) {
        int co = tc * 2 + r;
        float bv = fb[co];
#pragma unroll
        for (int c = 0; c < 4; c++) {
            int vg = bx * 64 + tv * 4 + c;
            int b = vg >> 15, v = vg & 32767;
            out[(((size_t)(b * 32 + co)) << 15) + v] = acc[r][c] + bv;
        }
    }
}

// ---------------------------------------------------------------------------
// block reduce + sub-slotted atomics (one co per block)
// ---------------------------------------------------------------------------
DEV void red_stats(float s, float s2, float sm, float* sred, float* mcnt,
                   int co, int sub, bool doMask) {
#pragma unroll
    for (int off = 32; off; off >>= 1) {
        s  += __shfl_down(s, off, 64);
        s2 += __shfl_down(s2, off, 64);
        sm += __shfl_down(sm, off, 64);
    }
    __shared__ float red[12];
    int lane = threadIdx.x & 63, wvi = threadIdx.x >> 6;
    if (!lane) { red[wvi] = s; red[4 + wvi] = s2; red[8 + wvi] = sm; }
    __syncthreads();
    if (!threadIdx.x) {
        atomicAdd(&sred[co * 32 + sub * 3],     red[0] + red[1] + red[2] + red[3]);
        atomicAdd(&sred[co * 32 + sub * 3 + 1], red[4] + red[5] + red[6] + red[7]);
        if (doMask) atomicAdd(&mcnt[sub * 4],   red[8] + red[9] + red[10] + red[11]);
    }
}

// ---------------------------------------------------------------------------
// post: sum SPLITK partials + bias + mask + LeakyReLU + stats
// ---------------------------------------------------------------------------
template<int COUT, int LOGDO, int SPLITK, int ITERS>
DEV void post_body(const float* __restrict__ bias, const float* __restrict__ m2,
                   const float* p, float* y, float* sred, float* mcnt) {
    constexpr int Dvox = 1 << (3 * LOGDO);
    constexpr size_t STR = (size_t)2 * COUT * Dvox;
    constexpr int LOGC = (COUT == 128) ? 7 : ((COUT == 64) ? 6 : 5);
    int base = blockIdx.x * (ITERS * 256);
    int co = (base >> (3 * LOGDO)) & (COUT - 1);
    float s = 0.f, s2 = 0.f, sm = 0.f;
#pragma unroll
    for (int it = 0; it < ITERS; it++) {
        int idx = base + it * 256 + threadIdx.x;
        int v = idx & (Dvox - 1);
        int b = idx >> (3 * LOGDO + LOGC);
        float sum = 0.f;
#pragma unroll
        for (int k = 0; k < SPLITK; k++) sum += p[k * STR + idx];
        float mv = m2[((size_t)b << (3 * LOGDO)) + v];
        float yv = (sum + bias[co]) * mv;
        yv = yv >= 0.f ? yv : 0.01f * yv;
        y[idx] = yv;
        s += yv; s2 += yv * yv; sm += mv;
    }
    red_stats(s, s2, sm, sred, mcnt, co, blockIdx.x & 7, co == 0);
}

__global__ __launch_bounds__(256) void post2_kernel(const float* b) { post_body<64, 4, 8, 1>(b, g_m2, g_p2, g_y2, g_sred + 4096, g_mcnt + 32); }
__global__ __launch_bounds__(256) void post3_kernel(const float* b) { post_body<128, 3, 32, 1>(b, g_m3, g_p3, g_y3, g_sred + 8192, g_mcnt + 64); }
__global__ __launch_bounds__(256) void post4_kernel(const float* b) { post_body<128, 4, 8, 2>(b, g_mt1, g_p4, g_t1, g_sred + 12288, g_mcnt + 96); }

// ---------------------------------------------------------------------------
// bn fused with finalize (sub-slot aware), + fused next-mask blocks
// ---------------------------------------------------------------------------
template<int LOGC, int LOGD>
DEV void bn_fused_body(const float* __restrict__ y, ushort* __restrict__ out,
                       const float* __restrict__ sred, const float* __restrict__ mcnt,
                       const float* __restrict__ gm, const float* __restrict__ be,
                       const float* __restrict__ m2, int blk) {
    constexpr int C = 1 << LOGC, Dvox = 1 << LOGD;
    __shared__ float sc[C], sh[C];
    int tid = threadIdx.x;
    if (tid < C) {
        float n = 0.f, su = 0.f, sq = 0.f;
#pragma unroll
        for (int s = 0; s < 8; s++) {
            n += mcnt[s * 4];
            su += sred[tid * 32 + s * 3];
            sq += sred[tid * 32 + s * 3 + 1];
        }
        n = fmaxf(n, 1.f);
        float mean = su / n;
        float var = fmaxf(sq / n - mean * mean, 0.f);
        float rstd = rsqrtf(var + 1e-5f);
        float s = gm[tid] * rstd;
        sc[tid] = s; sh[tid] = be[tid] - mean * s;
    }
    __syncthreads();
    int gv = blk * 256 + tid;
    int b = gv >> LOGD, vox = gv & (Dvox - 1);
    float mv = m2[gv];
    const float* yp = y + (((size_t)b << LOGC) << LOGD) + vox;
    ushort* op = out + (size_t)gv * C;
#pragma unroll
    for (int c0 = 0; c0 < C; c0 += 8) {
        ushort pk[8];
#pragma unroll
        for (int j = 0; j < 8; j++) {
            int c = c0 + j;
            float val = yp[(size_t)c << LOGD];
            pk[j] = f2bf((val * sc[c] + sh[c]) * mv);
        }
        *(ushort8*)&op[c0] = (ushort8){pk[0], pk[1], pk[2], pk[3], pk[4], pk[5], pk[6], pk[7]};
    }
}

__global__ __launch_bounds__(256)
void bn1_kernel(const float* g, const float* be) {          // grid 288
    if (blockIdx.x < 256) bn_fused_body<5, 15>(g_y1, g_y1b, g_sred + 0, g_mcnt + 0, g, be, g_m1, blockIdx.x);
    else mask_down_blk(g_m1, g_m2, 5, 4, blockIdx.x - 256);
}
__global__ __launch_bounds__(256)
void bn2_kernel(const float* g, const float* be) {          // grid 36
    if (blockIdx.x < 32) bn_fused_body<6, 12>(g_y2, g_y2b, g_sred + 4096, g_mcnt + 32, g, be, g_m2, blockIdx.x);
    else mask_down_blk(g_m2, g_m3, 4, 3, blockIdx.x - 32);
}
__global__ __launch_bounds__(256)
void bn3_kernel(const float* g, const float* be) {          // grid 36
    if (blockIdx.x < 4) bn_fused_body<7, 9>(g_y3, g_y3b, g_sred + 8192, g_mcnt + 64, g, be, g_m3, blockIdx.x);
    else mask_up_blk(g_m3, g_mt1, 3, 4, blockIdx.x - 4);
}
__global__ __launch_bounds__(256)
void bn4_kernel(const float* g, const float* be) {          // grid 288
    if (blockIdx.x < 32) bn_fused_body<7, 12>(g_t1, g_t1b, g_sred + 12288, g_mcnt + 96, g, be, g_mt1, blockIdx.x);
    else mask_up_blk(g_mt1, g_mt2, 4, 5, blockIdx.x - 32);
}

// ---------------------------------------------------------------------------

extern "C" void kernel_launch(void* const* d_in, const int* in_sizes, int n_in,
                              void* d_out, int out_size, void* d_ws, size_t ws_size,
                              hipStream_t stream) {
    (void)in_sizes; (void)n_in; (void)out_size; (void)d_ws; (void)ws_size;
    const float* feat = (const float*)d_in[0];
    const float* mask = (const float*)d_in[1];
    const float* w1  = (const float*)d_in[2];
    const float* b1  = (const float*)d_in[3];
    const float* g1  = (const float*)d_in[4];
    const float* be1 = (const float*)d_in[5];
    const float* w2  = (const float*)d_in[6];
    const float* b2  = (const float*)d_in[7];
    const float* g2  = (const float*)d_in[8];
    const float* be2 = (const float*)d_in[9];
    const float* w3  = (const float*)d_in[10];
    const float* b3  = (const float*)d_in[11];
    const float* g3  = (const float*)d_in[12];
    const float* be3 = (const float*)d_in[13];
    const float* tw1 = (const float*)d_in[14];
    const float* tb1 = (const float*)d_in[15];
    const float* tg1 = (const float*)d_in[16];
    const float* tbe1= (const float*)d_in[17];
    const float* tw2 = (const float*)d_in[18];
    const float* tb2 = (const float*)d_in[19];
    const float* tg2 = (const float*)d_in[20];
    const float* tbe2= (const float*)d_in[21];
    const float* fw  = (const float*)d_in[22];
    const float* fb  = (const float*)d_in[23];

    prep_all_kernel<<<11104, 256, 0, stream>>>(w1, fw, w2, w3, tw1, tw2, feat, mask);

    // block 1 (bf16 MFMA + fused stats): 4->32, 64^3 -> 32^3
    conv1_kernel<<<1024, 256, 0, stream>>>(b1);
    bn1_kernel<<<288, 256, 0, stream>>>(g1, be1);          // + mask2

    // block 2 (MFMA): 32->64, 32^3 -> 16^3, K=2048 split 8
    conv2_kernel<<<dim3(64, 1, 8), 256, 0, stream>>>();
    post2_kernel<<<2048, 256, 0, stream>>>(b2);
    bn2_kernel<<<36, 256, 0, stream>>>(g2, be2);           // + mask3

    // block 3 (MFMA): 64->128, 16^3 -> 8^3, K=4096 split 32
    conv3_kernel<<<dim3(16, 1, 32), 256, 0, stream>>>();
    post3_kernel<<<512, 256, 0, stream>>>(b3);
    bn3_kernel<<<36, 256, 0, stream>>>(g3, be3);           // + mask4

    // up block 1 (MFMA): 128->128, 8^3 -> 16^3, parity 8 x split 8
    conv4_kernel<<<dim3(8, 1, 64), 256, 0, stream>>>();
    post4_kernel<<<2048, 256, 0, stream>>>(tb1);
    bn4_kernel<<<288, 256, 0, stream>>>(tg1, tbe1);        // + mask5

    // up block 2 (MFMA + fused bias/mask/leaky/stats): 128->64, 16^3 -> 32^3
    conv5_kernel<<<dim3(64, 1, 8), 256, 0, stream>>>(tb2);

    // final dense 1x1x1 conv 64->32 @ 32^3 (BN finalize + apply fused on load)
    final_kernel<<<1024, 256, 0, stream>>>(fb, tg2, tbe2, (float*)d_out);
}

// Round 14
// 277.434 us; speedup vs baseline: 1.0813x; 1.0813x over previous
//
#include <hip/hip_runtime.h>
#include <hip/hip_bf16.h>

#define DEV static __device__ __forceinline__

typedef unsigned short ushort;
typedef __attribute__((ext_vector_type(8))) short short8;
typedef __attribute__((ext_vector_type(8))) ushort ushort8;
typedef __attribute__((ext_vector_type(4))) ushort ushortx4;
typedef __attribute__((ext_vector_type(4))) float accv;

DEV ushort f2bf(float f) {
    __hip_bfloat16 h = __float2bfloat16(f);   // RNE
    return reinterpret_cast<ushort&>(h);
}

// ---------------------------------------------------------------------------
// Static device workspace
// ---------------------------------------------------------------------------
__device__ float    g_sred[5 * 128 * 32];             // [l][co][32]: 0=sum 1=sumsq 2=maskcnt
__device__ float    g_y1[2097152];                    // (2,32,32^3) fp32 NCV
__device__ __align__(16) ushort g_y1b[2097152];       // (2,32^3,32) bf16 VC
__device__ float    g_m1[65536];
__device__ float    g_y2[524288];
__device__ __align__(16) ushort g_y2b[524288];        // (2,16^3,64) bf16 VC
__device__ float    g_m2[8192];
__device__ float    g_y3[131072];
__device__ __align__(16) ushort g_y3b[131072];        // (2,8^3,128) bf16 VC
__device__ float    g_m3[1024];
__device__ float    g_t1[1048576];
__device__ __align__(16) ushort g_t1b[1048576];       // (2,16^3,128) bf16 VC
__device__ float    g_mt1[8192];
__device__ float    g_mt2[65536];
__device__ float    g_t2[4194304];                    // conv5 raw out (fp32 NCV)
__device__ __align__(16) ushort g_x0b[2097152];       // (2,64^3,4) bf16 VC masked feat
// split-K partial buffers
__device__ float    g_p2[4194304];                    // 8  x 524288
__device__ float    g_p3[4194304];                    // 32 x 131072
__device__ float    g_p4[8388608];                    // 8  x 1048576
// K-major weights
__device__ __align__(16) ushort g_wb1[8192];          // [32co][256k] bf16, k=tap*4+ci
__device__ __align__(16) ushort g_wb2[131072];
__device__ __align__(16) ushort g_wb3[524288];
__device__ __align__(16) ushort g_wb4[1048576];
__device__ __align__(16) ushort g_wb5[524288];
__device__ float    g_fwt[2048];                      // [k=64][co=32] fp32

// ---------------------------------------------------------------------------
// prep_all (verified round-11/12)
// ---------------------------------------------------------------------------
__global__ __launch_bounds__(256)
void prep_all_kernel(const float* __restrict__ w1, const float* __restrict__ fw,
                     const float* __restrict__ w2, const float* __restrict__ w3,
                     const float* __restrict__ tw1, const float* __restrict__ tw2,
                     const float* __restrict__ feat, const float* __restrict__ mask) {
    int blk = blockIdx.x, tid = threadIdx.x;
    if (blk < 96) {
        int idx = blk * 256 + tid;
        if (idx < 20480) g_sred[idx] = 0.f;
        if (idx < 8192) {
            int co = idx >> 8, r = idx & 255;
            int tap = r >> 2, ci = r & 3;
            g_wb1[idx] = f2bf(w1[co * 256 + ci * 64 + tap]);
        }
        if (idx < 2048) { int co = idx >> 6, kg = idx & 63; g_fwt[kg * 32 + co] = fw[idx]; }
    } else if (blk < 608) {
        int idx = (blk - 96) * 256 + tid;
        int co = idx / 2048, r = idx % 2048;
        int ci = r >> 6, tap = r & 63;
        g_wb2[(size_t)co * 2048 + tap * 32 + ci] = f2bf(w2[idx]);
    } else if (blk < 2656) {
        int idx = (blk - 608) * 256 + tid;
        int co = idx / 4096, r = idx % 4096;
        int ci = r >> 6, tap = r & 63;
        g_wb3[(size_t)co * 4096 + tap * 64 + ci] = f2bf(w3[idx]);
    } else if (blk < 6752) {
        int idx = (blk - 2656) * 256 + tid;
        int co = idx / 8192, r = idx % 8192;
        int ci = r >> 6, t64 = r & 63;
        int kd = t64 >> 4, kh = (t64 >> 2) & 3, kw = t64 & 3;
        int pd = (3 - kd) & 1, td = (3 - kd) >> 1;
        int ph = (3 - kh) & 1, th = (3 - kh) >> 1;
        int pw = (3 - kw) & 1, tw = (3 - kw) >> 1;
        int parity = pd * 4 + ph * 2 + pw, t = td * 4 + th * 2 + tw;
        g_wb4[(((size_t)parity * 128 + co) * 8 + t) * 128 + ci] = f2bf(tw1[idx]);
    } else if (blk < 8800) {
        int idx = (blk - 6752) * 256 + tid;
        int co = idx / 8192, r = idx % 8192;
        int ci = r >> 6, t64 = r & 63;
        int kd = t64 >> 4, kh = (t64 >> 2) & 3, kw = t64 & 3;
        int pd = (3 - kd) & 1, td = (3 - kd) >> 1;
        int ph = (3 - kh) & 1, th = (3 - kh) >> 1;
        int pw = (3 - kw) & 1, tw = (3 - kw) >> 1;
        int parity = pd * 4 + ph * 2 + pw, t = td * 4 + th * 2 + tw;
        g_wb5[(((size_t)parity * 64 + co) * 8 + t) * 128 + ci] = f2bf(tw2[idx]);
    } else if (blk < 10848) {
        int idx = (blk - 8800) * 256 + tid;
        int b = idx >> 18, v = idx & 0x3FFFF;
        float mv = mask[idx] > 0.5f ? 1.f : 0.f;
        ushort pk[4];
#pragma unroll
        for (int c = 0; c < 4; c++) pk[c] = f2bf(feat[((b * 4 + c) << 18) + v] * mv);
        *(ushortx4*)&g_x0b[(size_t)idx * 4] = (ushortx4){pk[0], pk[1], pk[2], pk[3]};
    } else {
        int idx = (blk - 10848) * 256 + tid;            // mask1: 65536
        int b = idx >> 15, v = idx & 0x7FFF;
        int od = v >> 10, rem = v & 1023;
        int oh = rem >> 5, ow = rem & 31;
        const float* mp = mask + ((size_t)b << 18);
        float acc = 0.f;
        for (int kd = 0; kd < 4; kd++) {
            int id = 2 * od - 1 + kd;
            if ((unsigned)id >= 64u) continue;
            for (int kh = 0; kh < 4; kh++) {
                int ih = 2 * oh - 1 + kh;
                if ((unsigned)ih >= 64u) continue;
                const float* row = mp + ((size_t)id * 64 + ih) * 64;
                for (int kw = 0; kw < 4; kw++) {
                    int iw = 2 * ow - 1 + kw;
                    if ((unsigned)iw < 64u && row[iw] > 0.5f) acc += 1.f;
                }
            }
        }
        g_m1[idx] = acc > 0.f ? 1.f : 0.f;
    }
}

// ---------------------------------------------------------------------------
// mask dilation bodies with explicit block index (fused into bn kernels)
// ---------------------------------------------------------------------------
DEV void mask_down_blk(const float* mprev, float* mout, int logDin, int logDo, int blk) {
    int Din = 1 << logDin, Do = 1 << logDo;
    int idx = blk * 256 + threadIdx.x;
    int b = idx >> (3 * logDo), v = idx & ((1 << (3 * logDo)) - 1);
    int od = v >> (2 * logDo), rem = v & ((1 << (2 * logDo)) - 1);
    int oh = rem >> logDo, ow = rem & (Do - 1);
    const float* mp = mprev + ((size_t)b << (3 * logDin));
    float acc = 0.f;
    for (int kd = 0; kd < 4; kd++) {
        int id = 2 * od - 1 + kd;
        if ((unsigned)id >= (unsigned)Din) continue;
        for (int kh = 0; kh < 4; kh++) {
            int ih = 2 * oh - 1 + kh;
            if ((unsigned)ih >= (unsigned)Din) continue;
            const float* row = mp + ((size_t)id * Din + ih) * Din;
            for (int kw = 0; kw < 4; kw++) {
                int iw = 2 * ow - 1 + kw;
                if ((unsigned)iw < (unsigned)Din) acc += row[iw];
            }
        }
    }
    mout[idx] = acc > 0.f ? 1.f : 0.f;
}

DEV void mask_up_blk(const float* mprev, float* mout, int logDin, int logDo, int blk) {
    int Din = 1 << logDin, Do = 1 << logDo;
    int idx = blk * 256 + threadIdx.x;
    int b = idx >> (3 * logDo), v = idx & ((1 << (3 * logDo)) - 1);
    int od = v >> (2 * logDo), rem = v & ((1 << (2 * logDo)) - 1);
    int oh = rem >> logDo, ow = rem & (Do - 1);
    const float* mp = mprev + ((size_t)b << (3 * logDin));
    float acc = 0.f;
    for (int kd = 0; kd < 4; kd++) {
        int u = od + kd - 2; if (u < 0 || (u & 1)) continue;
        int id = u >> 1; if (id >= Din) continue;
        for (int kh = 0; kh < 4; kh++) {
            int uh = oh + kh - 2; if (uh < 0 || (uh & 1)) continue;
            int ih = uh >> 1; if (ih >= Din) continue;
            const float* row = mp + ((size_t)id * Din + ih) * Din;
            for (int kw = 0; kw < 4; kw++) {
                int uw = ow + kw - 2; if (uw < 0 || (uw & 1)) continue;
                int iw = uw >> 1; if (iw >= Din) continue;
                acc += row[iw];
            }
        }
    }
    mout[idx] = acc > 0.f ? 1.f : 0.f;
}

// ---------------------------------------------------------------------------
// bf16 MFMA implicit-GEMM, register-prefetch pipelined, hoisted B-decode.
// ---------------------------------------------------------------------------
template<int MODE, int MT, int NT, int CIN, int COUT, int LOGDI, int LOGDO, int SPLITK>
DEV void mfma_gemm_body(const ushort* __restrict__ xb, const ushort* __restrict__ wb,
                        float* __restrict__ y) {
    constexpr int KT = 32;
    constexpr int K  = (MODE == 1) ? CIN * 8 : CIN * 64;
    constexpr int KSEG = K / SPLITK;
    constexpr int LDA = 40;
    constexpr int MTW = MT / 32, NTW = NT / 32;
    constexpr int AR = MT * 4 / 256, BR = NT * 4 / 256;
    constexpr int LCIN = (CIN == 32) ? 5 : ((CIN == 64) ? 6 : 7);
    constexpr int Din = 1 << LOGDI, Do = 1 << LOGDO;
    constexpr int DvoxI = 1 << (3 * LOGDI), DvoxO = 1 << (3 * LOGDO);

    __shared__ __align__(16) ushort As[MT * LDA];
    __shared__ __align__(16) ushort Bs[NT * LDA];

    const int tid = threadIdx.x;
    const int bx = blockIdx.x;
    int pd = 0, ph = 0, pw = 0, ks = 0;
    const ushort* wp = wb;
    if constexpr (MODE == 1) {
        int z = blockIdx.z;
        pd = (z >> 2) & 1; ph = (z >> 1) & 1; pw = z & 1; ks = z >> 3;
        wp = wb + (size_t)(z & 7) * COUT * CIN * 8;
    } else {
        ks = blockIdx.z;
    }

    const int wv = tid >> 6, lane = tid & 63;
    const int mw = wv & 1, nw = wv >> 1;
    const int lr = lane & 15, quad = lane >> 4;

    // hoisted per-slot B voxel decode
    int rB[BR], dB[BR], hB[BR], wBv[BR];
#pragma unroll
    for (int r = 0; r < BR; r++) {
        int slot = r * 256 + tid;
        int n = slot >> 2;
        int vg = bx * NT + n;
        if constexpr (MODE == 0) {
            rB[r] = vg >> (3 * LOGDO);
            int vv = vg & (DvoxO - 1);
            dB[r] = 2 * (vv >> (2 * LOGDO)) - 1;
            hB[r] = 2 * ((vv >> LOGDO) & (Do - 1)) - 1;
            wBv[r] = 2 * (vv & (Do - 1)) - 1;
        } else {
            rB[r] = vg >> (3 * LOGDI);
            int vv = vg & (DvoxI - 1);
            dB[r] = (vv >> (2 * LOGDI)) + pd - 1;
            hB[r] = ((vv >> LOGDI) & (Din - 1)) + ph - 1;
            wBv[r] = (vv & (Din - 1)) + pw - 1;
        }
    }

    auto gatherA = [&](int kt, ushort8* pa) {
#pragma unroll
        for (int r = 0; r < AR; r++) {
            int slot = r * 256 + tid;
            int m = slot >> 2, oct = slot & 3;
            pa[r] = *(const ushort8*)&wp[(size_t)m * K + kt + oct * 8];
        }
    };
    auto gatherB = [&](int kt, ushort8* pb) {
        int tap = kt >> LCIN;
        int cib = kt & (CIN - 1);
        int id_d, ih_d, iw_d;
        if constexpr (MODE == 0) { id_d = tap >> 4; ih_d = (tap >> 2) & 3; iw_d = tap & 3; }
        else                     { id_d = (tap >> 2) & 1; ih_d = (tap >> 1) & 1; iw_d = tap & 1; }
#pragma unroll
        for (int r = 0; r < BR; r++) {
            int oct = (r * 256 + tid) & 3;
            int ci0 = cib + oct * 8;
            int id = dB[r] + id_d, ih = hB[r] + ih_d, iw = wBv[r] + iw_d;
            ushort8 v = (ushort8){0, 0, 0, 0, 0, 0, 0, 0};
            if ((unsigned)id < (unsigned)Din && (unsigned)ih < (unsigned)Din &&
                (unsigned)iw < (unsigned)Din)
                v = *(const ushort8*)&xb[((size_t)rB[r] * DvoxI +
                                          (id << (2 * LOGDI)) + (ih << LOGDI) + iw) * CIN + ci0];
            pb[r] = v;
        }
    };

    accv acc[MTW][NTW];
#pragma unroll
    for (int mt = 0; mt < MTW; mt++)
#pragma unroll
        for (int nt = 0; nt < NTW; nt++) acc[mt][nt] = (accv){0.f, 0.f, 0.f, 0.f};

    const int kbeg = ks * KSEG, kend = kbeg + KSEG;
    ushort8 pa[AR], pb[BR], qa[AR], qb[BR];
    gatherA(kbeg, pa);
    gatherB(kbeg, pb);

    for (int kt = kbeg; kt < kend; kt += KT) {
        __syncthreads();
#pragma unroll
        for (int r = 0; r < AR; r++) {
            int slot = r * 256 + tid;
            int m = slot >> 2, oct = slot & 3;
            *(ushort8*)&As[m * LDA + oct * 8] = pa[r];
        }
#pragma unroll
        for (int r = 0; r < BR; r++) {
            int slot = r * 256 + tid;
            int n = slot >> 2, oct = slot & 3;
            *(ushort8*)&Bs[n * LDA + oct * 8] = pb[r];
        }
        __syncthreads();
        bool more = (kt + KT) < kend;
        if (more) { gatherA(kt + KT, qa); gatherB(kt + KT, qb); }

        short8 af[MTW], bfr[NTW];
#pragma unroll
        for (int mt = 0; mt < MTW; mt++)
            af[mt] = *(const short8*)&As[((mw * MTW + mt) * 16 + lr) * LDA + quad * 8];
#pragma unroll
        for (int nt = 0; nt < NTW; nt++)
            bfr[nt] = *(const short8*)&Bs[((nw * NTW + nt) * 16 + lr) * LDA + quad * 8];
#pragma unroll
        for (int mt = 0; mt < MTW; mt++)
#pragma unroll
            for (int nt = 0; nt < NTW; nt++)
                acc[mt][nt] = __builtin_amdgcn_mfma_f32_16x16x32_bf16(
                    af[mt], bfr[nt], acc[mt][nt], 0, 0, 0);
        if (more) {
#pragma unroll
            for (int r = 0; r < AR; r++) pa[r] = qa[r];
#pragma unroll
            for (int r = 0; r < BR; r++) pb[r] = qb[r];
        }
    }

    float* yp = y + (size_t)ks * (2 * COUT * DvoxO);
#pragma unroll
    for (int mt = 0; mt < MTW; mt++) {
#pragma unroll
        for (int nt = 0; nt < NTW; nt++) {
#pragma unroll
            for (int r = 0; r < 4; r++) {
                int co = (mw * MTW + mt) * 16 + quad * 4 + r;
                int vg = bx * NT + (nw * NTW + nt) * 16 + lr;
                size_t idx;
                if constexpr (MODE == 1) {
                    int b = vg >> (3 * LOGDI);
                    int vv = vg & (DvoxI - 1);
                    int odp = vv >> (2 * LOGDI), ohp = (vv >> LOGDI) & (Din - 1), owp = vv & (Din - 1);
                    int od = 2 * odp + pd, oh = 2 * ohp + ph, ow = 2 * owp + pw;
                    idx = (((size_t)(b * COUT + co)) << (3 * LOGDO)) +
                          (od << (2 * LOGDO)) + (oh << LOGDO) + ow;
                } else {
                    int b = vg >> (3 * LOGDO);
                    int off = vg & (DvoxO - 1);
                    idx = (((size_t)(b * COUT + co)) << (3 * LOGDO)) + off;
                }
                yp[idx] = acc[mt][nt][r];
            }
        }
    }
}

__global__ __launch_bounds__(256)
void conv2_kernel() { mfma_gemm_body<0, 64, 128, 32, 64, 5, 4, 8>(g_y1b, g_wb2, g_p2); }
__global__ __launch_bounds__(256)
void conv3_kernel() { mfma_gemm_body<0, 128, 64, 64, 128, 4, 3, 32>(g_y2b, g_wb3, g_p3); }
__global__ __launch_bounds__(256)
void conv4_kernel() { mfma_gemm_body<1, 128, 128, 128, 128, 3, 4, 8>(g_y3b, g_wb4, g_p4); }
__global__ __launch_bounds__(256)
void conv5_kernel() { mfma_gemm_body<1, 64, 128, 128, 64, 4, 5, 1>(g_t1b, g_wb5, g_t2); }

// ---------------------------------------------------------------------------
// conv1: bf16 MFMA (verified round-11)
// ---------------------------------------------------------------------------
__global__ __launch_bounds__(256)
void conv1_kernel(const float* __restrict__ bias) {
    constexpr int LDA = 40;
    __shared__ __align__(16) ushort As[32 * LDA];
    __shared__ __align__(16) ushort Bs[64 * LDA];
    const int tid = threadIdx.x, bx = blockIdx.x;
    const int wv = tid >> 6, lane = tid & 63;
    const int lr = lane & 15, quad = lane >> 4;

    const int nB = tid >> 2, octB = tid & 3;
    const int vgB = bx * 64 + nB;
    const int bB = vgB >> 15, vB = vgB & 32767;
    const int odB = vB >> 10, ohB = (vB >> 5) & 31, owB = vB & 31;

    auto gatherA = [&](int kt, ushort8& pa) {
        if (tid < 128) {
            int m = tid >> 2, oct = tid & 3;
            pa = *(const ushort8*)&g_wb1[m * 256 + kt + oct * 8];
        }
    };
    auto gatherB = [&](int kt, ushort8& pb) {
        int kg0 = kt + octB * 8;
        int t0 = kg0 >> 2;
        int kd = t0 >> 4, kh = (t0 >> 2) & 3, kw0 = t0 & 3;
        int id = 2 * odB - 1 + kd;
        int ih = 2 * ohB - 1 + kh;
        int iw0 = 2 * owB - 1 + kw0;
        ushort8 v = (ushort8){0, 0, 0, 0, 0, 0, 0, 0};
        if ((unsigned)id < 64u && (unsigned)ih < 64u) {
            const ushort* base = g_x0b + ((((size_t)bB << 18) + (id << 12) + (ih << 6)) << 2);
            if (iw0 >= 0 && iw0 + 1 < 64) {
                v = *(const ushort8*)&base[iw0 << 2];
            } else {
                if ((unsigned)iw0 < 64u) {
                    ushortx4 h = *(const ushortx4*)&base[iw0 << 2];
                    v[0] = h[0]; v[1] = h[1]; v[2] = h[2]; v[3] = h[3];
                }
                if ((unsigned)(iw0 + 1) < 64u) {
                    ushortx4 h = *(const ushortx4*)&base[(iw0 + 1) << 2];
                    v[4] = h[0]; v[5] = h[1]; v[6] = h[2]; v[7] = h[3];
                }
            }
        }
        pb = v;
    };

    accv acc[2];
    acc[0] = (accv){0.f, 0.f, 0.f, 0.f};
    acc[1] = (accv){0.f, 0.f, 0.f, 0.f};
    ushort8 pa, pb, qa, qb;
    gatherA(0, pa); gatherB(0, pb);

    for (int kt = 0; kt < 256; kt += 32) {
        __syncthreads();
        if (tid < 128) { int m = tid >> 2, oct = tid & 3; *(ushort8*)&As[m * LDA + oct * 8] = pa; }
        *(ushort8*)&Bs[nB * LDA + octB * 8] = pb;
        __syncthreads();
        bool more = kt < 224;
        if (more) { gatherA(kt + 32, qa); gatherB(kt + 32, qb); }

        short8 b8 = *(const short8*)&Bs[(wv * 16 + lr) * LDA + quad * 8];
#pragma unroll
        for (int mt = 0; mt < 2; mt++) {
            short8 a8 = *(const short8*)&As[(mt * 16 + lr) * LDA + quad * 8];
            acc[mt] = __builtin_amdgcn_mfma_f32_16x16x32_bf16(a8, b8, acc[mt], 0, 0, 0);
        }
        if (more) { pa = qa; pb = qb; }
    }

#pragma unroll
    for (int mt = 0; mt < 2; mt++) {
#pragma unroll
        for (int r = 0; r < 4; r++) {
            int co = mt * 16 + quad * 4 + r;
            int vg = bx * 64 + wv * 16 + lr;
            int b = vg >> 15, off = vg & 32767;
            float mv = g_m1[((size_t)b << 15) + off];
            float yv = (acc[mt][r] + bias[co]) * mv;
            yv = yv >= 0.f ? yv : 0.01f * yv;
            g_y1[(((size_t)(b * 32 + co)) << 15) + off] = yv;
        }
    }
}

// ---------------------------------------------------------------------------
// final: fp32 1x1x1, fully fused load: bias5+mask+leaky+BN. grid 1024.
// ---------------------------------------------------------------------------
__global__ __launch_bounds__(256)
void final_kernel(const float* __restrict__ fb, const float* __restrict__ b5,
                  const float* __restrict__ tg2, const float* __restrict__ tbe2,
                  float* __restrict__ out) {
    __shared__ float As[1024];
    __shared__ float Bs[2048];
    __shared__ float sc5[64], sh5[64], bb5[64];
    const int tid = threadIdx.x, tc = tid & 15, tv = tid >> 4;
    const int bx = blockIdx.x;

    if (tid < 64) {
        const float* sred = g_sred + 16384;
        float n = fmaxf(sred[tid * 32 + 2], 1.f);
        float mean = sred[tid * 32] / n;
        float var = fmaxf(sred[tid * 32 + 1] / n - mean * mean, 0.f);
        float rstd = rsqrtf(var + 1e-5f);
        float s = tg2[tid] * rstd;
        sc5[tid] = s; sh5[tid] = tbe2[tid] - mean * s; bb5[tid] = b5[tid];
    }

    float acc[2][4] = {{0.f}};
    for (int kt = 0; kt < 64; kt += 32) {
        __syncthreads();
#pragma unroll
        for (int e = 0; e < 4; e++) As[e * 256 + tid] = g_fwt[kt * 32 + e * 256 + tid];
#pragma unroll
        for (int e = 0; e < 8; e++) {
            int j = e * 256 + tid;
            int kk = j >> 6, n = j & 63;
            int kg = kt + kk;
            int vg = bx * 64 + n;
            int b = vg >> 15, v = vg & 32767;
            float raw = g_t2[(((size_t)(b * 64 + kg)) << 15) + v];
            float mv = g_mt2[((size_t)b << 15) + v];
            float t = (raw + bb5[kg]) * mv;
            t = t >= 0.f ? t : 0.01f * t;
            Bs[kk * 64 + n] = (t * sc5[kg] + sh5[kg]) * mv;
        }
        __syncthreads();
#pragma unroll
        for (int kk = 0; kk < 32; kk++) {
            float2 a2 = *(const float2*)&As[kk * 32 + tc * 2];
            float4 b4 = *(const float4*)&Bs[kk * 64 + tv * 4];
            float a[2] = {a2.x, a2.y};
            float bb[4] = {b4.x, b4.y, b4.z, b4.w};
#pragma unroll
            for (int r = 0; r < 2; r++)
#pragma unroll
                for (int c = 0; c < 4; c++) acc[r][c] = fmaf(a[r], bb[c], acc[r][c]);
        }
    }
#pragma unroll
    for (int r = 0; r < 2; r++) {
        int co = tc * 2 + r;
        float bv = fb[co];
#pragma unroll
        for (int c = 0; c < 4; c++) {
            int vg = bx * 64 + tv * 4 + c;
            int b = vg >> 15, v = vg & 32767;
            out[(((size_t)(b * 32 + co)) << 15) + v] = acc[r][c] + bv;
        }
    }
}

// ---------------------------------------------------------------------------
DEV void red3_and_atomic(float s, float s2, float sm, float* sred, int co) {
#pragma unroll
    for (int off = 32; off; off >>= 1) {
        s  += __shfl_down(s, off, 64);
        s2 += __shfl_down(s2, off, 64);
        sm += __shfl_down(sm, off, 64);
    }
    __shared__ float red[12];
    int lane = threadIdx.x & 63, wvi = threadIdx.x >> 6;
    if (!lane) { red[wvi] = s; red[4 + wvi] = s2; red[8 + wvi] = sm; }
    __syncthreads();
    if (!threadIdx.x) {
        atomicAdd(&sred[co * 32 + 0], red[0] + red[1] + red[2] + red[3]);
        atomicAdd(&sred[co * 32 + 1], red[4] + red[5] + red[6] + red[7]);
        atomicAdd(&sred[co * 32 + 2], red[8] + red[9] + red[10] + red[11]);
    }
}

// ---------------------------------------------------------------------------
// post: sum SPLITK partials + bias + mask + LeakyReLU + stats (WRITE optional)
// ---------------------------------------------------------------------------
template<int COUT, int LOGDO, int SPLITK, int ITERS, bool WRITE>
DEV void post_body(const float* __restrict__ bias, const float* __restrict__ m2,
                   const float* p, float* y, float* sred) {
    constexpr int Dvox = 1 << (3 * LOGDO);
    constexpr size_t STR = (size_t)2 * COUT * Dvox;
    constexpr int LOGC = (COUT == 128) ? 7 : ((COUT == 64) ? 6 : 5);
    int base = blockIdx.x * (ITERS * 256);
    int co = (base >> (3 * LOGDO)) & (COUT - 1);
    float s = 0.f, s2 = 0.f, sm = 0.f;
#pragma unroll
    for (int it = 0; it < ITERS; it++) {
        int idx = base + it * 256 + threadIdx.x;
        int v = idx & (Dvox - 1);
        int b = idx >> (3 * LOGDO + LOGC);
        float sum = 0.f;
#pragma unroll
        for (int k = 0; k < SPLITK; k++) sum += p[k * STR + idx];
        float mv = m2[((size_t)b << (3 * LOGDO)) + v];
        float yv = (sum + bias[co]) * mv;
        yv = yv >= 0.f ? yv : 0.01f * yv;
        if constexpr (WRITE) y[idx] = yv;
        s += yv; s2 += yv * yv; sm += mv;
    }
    red3_and_atomic(s, s2, sm, sred, co);
}

__global__ __launch_bounds__(256) void post2_kernel(const float* b) { post_body<64, 4, 8, 1, true>(b, g_m2, g_p2, g_y2, g_sred + 4096); }
__global__ __launch_bounds__(256) void post3_kernel(const float* b) { post_body<128, 3, 32, 1, true>(b, g_m3, g_p3, g_y3, g_sred + 8192); }
__global__ __launch_bounds__(256) void post4_kernel(const float* b) { post_body<128, 4, 8, 2, true>(b, g_mt1, g_p4, g_t1, g_sred + 12288); }
__global__ __launch_bounds__(256) void post5_kernel(const float* b) { post_body<64, 5, 1, 8, false>(b, g_mt2, g_t2, g_t2, g_sred + 16384); }

// stats pass over y1. grid 2048.
__global__ __launch_bounds__(256)
void stats1_kernel() {
    int base = blockIdx.x * 1024;
    int co = (base >> 15) & 31;
    float s = 0.f, s2 = 0.f, sm = 0.f;
#pragma unroll
    for (int it = 0; it < 4; it++) {
        int idx = base + it * 256 + threadIdx.x;
        int v = idx & 32767;
        int b = idx >> 20;
        float yv = g_y1[idx];
        float mv = g_m1[((size_t)b << 15) + v];
        s += yv; s2 += yv * yv; sm += mv;
    }
    red3_and_atomic(s, s2, sm, g_sred, co);
}

// ---------------------------------------------------------------------------
// bn fused with finalize, explicit block index
// ---------------------------------------------------------------------------
template<int LOGC, int LOGD>
DEV void bn_fused_body(const float* __restrict__ y, ushort* __restrict__ out,
                       const float* __restrict__ sred, const float* __restrict__ gm,
                       const float* __restrict__ be, const float* __restrict__ m2,
                       int blk) {
    constexpr int C = 1 << LOGC, Dvox = 1 << LOGD;
    __shared__ float sc[C], sh[C];
    int tid = threadIdx.x;
    if (tid < C) {
        float n = fmaxf(sred[tid * 32 + 2], 1.f);
        float mean = sred[tid * 32] / n;
        float var = fmaxf(sred[tid * 32 + 1] / n - mean * mean, 0.f);
        float rstd = rsqrtf(var + 1e-5f);
        float s = gm[tid] * rstd;
        sc[tid] = s; sh[tid] = be[tid] - mean * s;
    }
    __syncthreads();
    int gv = blk * 256 + tid;
    int b = gv >> LOGD, vox = gv & (Dvox - 1);
    float mv = m2[gv];
    const float* yp = y + (((size_t)b << LOGC) << LOGD) + vox;
    ushort* op = out + (size_t)gv * C;
#pragma unroll
    for (int c0 = 0; c0 < C; c0 += 8) {
        ushort pk[8];
#pragma unroll
        for (int j = 0; j < 8; j++) {
            int c = c0 + j;
            float val = yp[(size_t)c << LOGD];
            pk[j] = f2bf((val * sc[c] + sh[c]) * mv);
        }
        *(ushort8*)&op[c0] = (ushort8){pk[0], pk[1], pk[2], pk[3], pk[4], pk[5], pk[6], pk[7]};
    }
}

// bn kernels with fused next-mask blocks
__global__ __launch_bounds__(256)
void bn1_kernel(const float* g, const float* be) {          // grid 288
    if (blockIdx.x < 256) bn_fused_body<5, 15>(g_y1, g_y1b, g_sred + 0, g, be, g_m1, blockIdx.x);
    else mask_down_blk(g_m1, g_m2, 5, 4, blockIdx.x - 256); // mask2: 32 blocks
}
__global__ __launch_bounds__(256)
void bn2_kernel(const float* g, const float* be) {          // grid 36
    if (blockIdx.x < 32) bn_fused_body<6, 12>(g_y2, g_y2b, g_sred + 4096, g, be, g_m2, blockIdx.x);
    else mask_down_blk(g_m2, g_m3, 4, 3, blockIdx.x - 32);  // mask3: 4 blocks
}
__global__ __launch_bounds__(256)
void bn3_kernel(const float* g, const float* be) {          // grid 36
    if (blockIdx.x < 4) bn_fused_body<7, 9>(g_y3, g_y3b, g_sred + 8192, g, be, g_m3, blockIdx.x);
    else mask_up_blk(g_m3, g_mt1, 3, 4, blockIdx.x - 4);    // mask4: 32 blocks
}
__global__ __launch_bounds__(256)
void bn4_kernel(const float* g, const float* be) {          // grid 288
    if (blockIdx.x < 32) bn_fused_body<7, 12>(g_t1, g_t1b, g_sred + 12288, g, be, g_mt1, blockIdx.x);
    else mask_up_blk(g_mt1, g_mt2, 4, 5, blockIdx.x - 32);  // mask5: 256 blocks
}

// ---------------------------------------------------------------------------

extern "C" void kernel_launch(void* const* d_in, const int* in_sizes, int n_in,
                              void* d_out, int out_size, void* d_ws, size_t ws_size,
                              hipStream_t stream) {
    (void)in_sizes; (void)n_in; (void)out_size; (void)d_ws; (void)ws_size;
    const float* feat = (const float*)d_in[0];
    const float* mask = (const float*)d_in[1];
    const float* w1  = (const float*)d_in[2];
    const float* b1  = (const float*)d_in[3];
    const float* g1  = (const float*)d_in[4];
    const float* be1 = (const float*)d_in[5];
    const float* w2  = (const float*)d_in[6];
    const float* b2  = (const float*)d_in[7];
    const float* g2  = (const float*)d_in[8];
    const float* be2 = (const float*)d_in[9];
    const float* w3  = (const float*)d_in[10];
    const float* b3  = (const float*)d_in[11];
    const float* g3  = (const float*)d_in[12];
    const float* be3 = (const float*)d_in[13];
    const float* tw1 = (const float*)d_in[14];
    const float* tb1 = (const float*)d_in[15];
    const float* tg1 = (const float*)d_in[16];
    const float* tbe1= (const float*)d_in[17];
    const float* tw2 = (const float*)d_in[18];
    const float* tb2 = (const float*)d_in[19];
    const float* tg2 = (const float*)d_in[20];
    const float* tbe2= (const float*)d_in[21];
    const float* fw  = (const float*)d_in[22];
    const float* fb  = (const float*)d_in[23];

    prep_all_kernel<<<11104, 256, 0, stream>>>(w1, fw, w2, w3, tw1, tw2, feat, mask);

    // block 1 (bf16 MFMA): 4->32, 64^3 -> 32^3
    conv1_kernel<<<1024, 256, 0, stream>>>(b1);
    stats1_kernel<<<2048, 256, 0, stream>>>();
    bn1_kernel<<<288, 256, 0, stream>>>(g1, be1);          // + mask2

    // block 2 (MFMA): 32->64, 32^3 -> 16^3, K=2048 split 8
    conv2_kernel<<<dim3(64, 1, 8), 256, 0, stream>>>();
    post2_kernel<<<2048, 256, 0, stream>>>(b2);
    bn2_kernel<<<36, 256, 0, stream>>>(g2, be2);           // + mask3

    // block 3 (MFMA): 64->128, 16^3 -> 8^3, K=4096 split 32
    conv3_kernel<<<dim3(16, 1, 32), 256, 0, stream>>>();
    post3_kernel<<<512, 256, 0, stream>>>(b3);
    bn3_kernel<<<36, 256, 0, stream>>>(g3, be3);           // + mask4

    // up block 1 (MFMA): 128->128, 8^3 -> 16^3, parity 8 x split 8
    conv4_kernel<<<dim3(8, 1, 64), 256, 0, stream>>>();
    post4_kernel<<<2048, 256, 0, stream>>>(tb1);
    bn4_kernel<<<288, 256, 0, stream>>>(tg1, tbe1);        // + mask5

    // up block 2 (MFMA): 128->64, 16^3 -> 32^3, parity 8, direct store
    conv5_kernel<<<dim3(64, 1, 8), 256, 0, stream>>>();
    post5_kernel<<<2048, 256, 0, stream>>>(tb2);           // stats only

    // final dense 1x1x1 conv 64->32 @ 32^3 (bias5+mask+leaky+BN fused on load)
    final_kernel<<<1024, 256, 0, stream>>>(fb, tb2, tg2, tbe2, (float*)d_out);
}